// Round 2
// baseline (385.390 us; speedup 1.0000x reference)
//
#include <hip/hip_runtime.h>

#define BATCH 4096
#define TT 512
#define HH 64
#define BT 16      // batch rows per block (one MFMA M-tile)
#define XS 516     // x_s row stride in floats (bank-spread, 16B-aligned rows)
#define HS 72      // h buffer row stride in bf16 (+8 pad: spreads A-frag banks, keeps 16B align)

typedef __attribute__((ext_vector_type(8))) short short8;
typedef __attribute__((ext_vector_type(4))) float floatx4;

__device__ __forceinline__ float sigf(float x) {
    return __builtin_amdgcn_rcpf(1.f + __builtin_amdgcn_exp2f(-1.44269504089f * x));
}
__device__ __forceinline__ float tanhf_(float x) {
    float e = __builtin_amdgcn_exp2f(2.88539008178f * x);   // e^(2x)
    return 1.f - 2.f * __builtin_amdgcn_rcpf(e + 1.f);
}
__device__ __forceinline__ unsigned short f2bf(float f) {   // RNE f32->bf16
    unsigned u = __float_as_uint(f);
    u = u + 0x7FFFu + ((u >> 16) & 1u);
    return (unsigned short)(u >> 16);
}

// 512 threads = 8 waves = 2 waves/SIMD. Waves w and w+4 duplicate the MFMA for
// gate-group (w&3) — MFMA util is ~10%, duplication is free — and split the
// expensive activations by accumulator row-pair (r = 2*(w>>2) + {0,1}), so
// per-wave transcendental issue halves and two waves/SIMD hide latency.
__global__ __launch_bounds__(512) void lstm_kernel(
    const float* __restrict__ x, const float* __restrict__ W_ih,
    const float* __restrict__ W_hh, const float* __restrict__ b_ih,
    const float* __restrict__ b_hh, const float* __restrict__ W_out,
    const float* __restrict__ b_out, float* __restrict__ out)
{
    __shared__ __align__(16) float x_s[BT * XS];
    __shared__ __align__(16) unsigned short hb[2][BT * HS];  // bf16 h, double-buffered
    __shared__ __align__(16) float hf[BT * 65];              // final h in fp32 for the head

    const int tid = threadIdx.x;
    const int w = tid >> 6;       // wave id 0..7
    const int gg = w & 3;         // gate-column group -> tiles {gg, gg+4, gg+8, gg+12}
    const int rh = w >> 2;        // row-half: activations for r in {2*rh, 2*rh+1}
    const int l = tid & 63;
    const int q = l >> 4;         // quad-of-16 within wave
    const int c = l & 15;
    const int n = 16 * gg + c;    // hidden index this lane owns for activations
    const int bbase = blockIdx.x * BT;

    // ---- stage x[bbase..bbase+15][0..511] into LDS, coalesced float4 ----
    for (int i = 0; i < 4; ++i) {
        int flat = i * 512 + tid;              // 2048 float4s
        int row = flat >> 7, c4 = flat & 127;
        const float4* xg = reinterpret_cast<const float4*>(x + (size_t)(bbase + row) * TT);
        float4 v = xg[c4];
        *reinterpret_cast<float4*>(&x_s[row * XS + c4 * 4]) = v;
    }
    for (int i = tid; i < BT * HS; i += 512) hb[0][i] = 0;   // h0 = 0

    // ---- persistent B-fragments: W_hh rows for gates g = 64*t + n, bf16, in VGPRs ----
    short8 bfr[4][2];
    float wih[4], bb[4];
    for (int t = 0; t < 4; ++t) {
        int g = 64 * t + n;
        wih[t] = W_ih[g];
        bb[t] = b_ih[g] + b_hh[g];
        for (int ks = 0; ks < 2; ++ks) {
            const float* wp = W_hh + g * 64 + ks * 32 + q * 8;
            short8 v;
            #pragma unroll
            for (int j = 0; j < 8; ++j) v[j] = (short)f2bf(wp[j]);
            bfr[t][ks] = v;
        }
    }
    float cst[2] = {0.f, 0.f};    // c-state for rows 4q + 2*rh + {0,1}, hidden n

    __syncthreads();

    int cur = 0;
    for (int ts = 0; ts < TT; ++ts) {
        const unsigned short* hc = hb[cur];
        short8 a0 = *reinterpret_cast<const short8*>(hc + c * HS + q * 8);
        short8 a1 = *reinterpret_cast<const short8*>(hc + c * HS + q * 8 + 32);

        float xr[4];
        #pragma unroll
        for (int r = 0; r < 4; ++r) xr[r] = x_s[(q * 4 + r) * XS + ts];

        floatx4 acc[4];
        #pragma unroll
        for (int t = 0; t < 4; ++t)
            #pragma unroll
            for (int r = 0; r < 4; ++r)
                acc[t][r] = fmaf(xr[r], wih[t], bb[t]);

        #pragma unroll
        for (int t = 0; t < 4; ++t) {
            acc[t] = __builtin_amdgcn_mfma_f32_16x16x32_bf16(a0, bfr[t][0], acc[t], 0, 0, 0);
            acc[t] = __builtin_amdgcn_mfma_f32_16x16x32_bf16(a1, bfr[t][1], acc[t], 0, 0, 0);
        }

        // activations: this wave handles only its 2 row-slots of the 4
        unsigned short* hnx = hb[cur ^ 1];
        #pragma unroll
        for (int rr = 0; rr < 2; ++rr) {
            int r = 2 * rh + rr;
            float ig = sigf(acc[0][r]);
            float fg = sigf(acc[1][r]);
            float gv = tanhf_(acc[2][r]);
            float og = sigf(acc[3][r]);
            float cv = fmaf(fg, cst[rr], ig * gv);
            cst[rr] = cv;
            float hv = og * tanhf_(cv);
            hnx[(q * 4 + r) * HS + n] = f2bf(hv);
            if (ts == TT - 1) hf[(q * 4 + r) * 65 + n] = hv;
        }
        cur ^= 1;
        __syncthreads();
    }

    // ---- head: out[b][o] = sum_n hf[b][n]*W_out[o][n] + b_out[o] ----
    if (tid < BT * 3) {
        int row = tid / 3, o = tid % 3;
        float s = b_out[o];
        #pragma unroll 8
        for (int k = 0; k < HH; ++k) s = fmaf(hf[row * 65 + k], W_out[o * 64 + k], s);
        out[(size_t)(bbase + row) * 3 + o] = s;
    }
}

extern "C" void kernel_launch(void* const* d_in, const int* in_sizes, int n_in,
                              void* d_out, int out_size, void* d_ws, size_t ws_size,
                              hipStream_t stream) {
    const float* x     = (const float*)d_in[0];
    const float* W_ih  = (const float*)d_in[1];
    const float* W_hh  = (const float*)d_in[2];
    const float* b_ih  = (const float*)d_in[3];
    const float* b_hh  = (const float*)d_in[4];
    const float* W_out = (const float*)d_in[5];
    const float* b_out = (const float*)d_in[6];
    float* out = (float*)d_out;
    hipLaunchKernelGGL(lstm_kernel, dim3(BATCH / BT), dim3(512), 0, stream,
                       x, W_ih, W_hh, b_ih, b_hh, W_out, b_out, out);
}

// Round 3
// 303.771 us; speedup vs baseline: 1.2687x; 1.2687x over previous
//
#include <hip/hip_runtime.h>

#define BATCH 4096
#define TT 512
#define HH 64
#define BT 8       // batch rows per block; 16-row MFMA tile half-garbage by design:
                   // batch j -> tile row m=4*(j>>1)+(j&1), so valid rows are r={0,1} for all lanes
#define XS 516     // x_s row stride in floats
#define HS 72      // h buffer row stride in bf16

typedef __attribute__((ext_vector_type(8))) short short8;
typedef __attribute__((ext_vector_type(4))) float floatx4;

__device__ __forceinline__ float sigf(float x) {
    return __builtin_amdgcn_rcpf(1.f + __builtin_amdgcn_exp2f(-1.44269504089f * x));
}
__device__ __forceinline__ float tanhf_(float x) {
    float e = __builtin_amdgcn_exp2f(2.88539008178f * x);   // e^(2x)
    return 1.f - 2.f * __builtin_amdgcn_rcpf(e + 1.f);
}
__device__ __forceinline__ unsigned short f2bf(float f) {   // RNE f32->bf16
    unsigned u = __float_as_uint(f);
    u = u + 0x7FFFu + ((u >> 16) & 1u);
    return (unsigned short)(u >> 16);
}

// 256 threads = 4 waves; grid 512 = 2 independent blocks/CU (independent
// barriers -> uncorrelated stalls, real latency hiding, unlike round 2's
// lockstepped 8-wave block). Wave w owns gate col-tiles {w,w+4,w+8,w+12}.
__global__ __launch_bounds__(256, 2) void lstm_kernel(
    const float* __restrict__ x, const float* __restrict__ W_ih,
    const float* __restrict__ W_hh, const float* __restrict__ b_ih,
    const float* __restrict__ b_hh, const float* __restrict__ W_out,
    const float* __restrict__ b_out, float* __restrict__ out)
{
    __shared__ __align__(16) float x_s[BT * XS];
    __shared__ __align__(16) unsigned short hb[2][16 * HS]; // bf16 h; rows m with (m&2) stay 0
    __shared__ __align__(16) float hf[BT * 65];             // final h fp32 for the head

    const int tid = threadIdx.x;
    const int w = tid >> 6;       // wave 0..3 -> gate col group
    const int l = tid & 63;
    const int q = l >> 4;
    const int c = l & 15;
    const int n = 16 * w + c;     // hidden index this lane activates
    const int bbase = blockIdx.x * BT;

    // ---- stage x[bbase..bbase+7][0..511] into LDS, coalesced float4 ----
    for (int i = 0; i < 4; ++i) {
        int flat = i * 256 + tid;              // 1024 float4s
        int row = flat >> 7, c4 = flat & 127;
        const float4* xg = reinterpret_cast<const float4*>(x + (size_t)(bbase + row) * TT);
        float4 v = xg[c4];
        *reinterpret_cast<float4*>(&x_s[row * XS + c4 * 4]) = v;
    }
    for (int i = tid; i < 2 * 16 * HS; i += 256) hb[0][i] = 0;  // h0=0 AND garbage rows of both bufs

    // ---- persistent B-fragments: W_hh rows for gates g = 64*t + n, bf16, in VGPRs ----
    short8 bfr[4][2];
    float wih[4], bb[4];
    for (int t = 0; t < 4; ++t) {
        int g = 64 * t + n;
        wih[t] = W_ih[g];
        bb[t] = b_ih[g] + b_hh[g];
        for (int ks = 0; ks < 2; ++ks) {
            const float* wp = W_hh + g * 64 + ks * 32 + q * 8;
            short8 v;
            #pragma unroll
            for (int j = 0; j < 8; ++j) v[j] = (short)f2bf(wp[j]);
            bfr[t][ks] = v;
        }
    }
    float cst[2] = {0.f, 0.f};    // c-state for batch rows 2q, 2q+1, hidden n

    __syncthreads();

    int cur = 0;
    for (int ts = 0; ts < TT; ++ts) {
        // A-frag: lane reads tile row m=c (garbage rows read zeros)
        const unsigned short* hc = hb[cur];
        short8 a0 = *reinterpret_cast<const short8*>(hc + c * HS + q * 8);
        short8 a1 = *reinterpret_cast<const short8*>(hc + c * HS + q * 8 + 32);

        float x0 = x_s[(2 * q) * XS + ts];
        float x1 = x_s[(2 * q + 1) * XS + ts];

        floatx4 acc[4];
        #pragma unroll
        for (int t = 0; t < 4; ++t) {
            acc[t][0] = fmaf(x0, wih[t], bb[t]);
            acc[t][1] = fmaf(x1, wih[t], bb[t]);
            acc[t][2] = 0.f;
            acc[t][3] = 0.f;
        }

        #pragma unroll
        for (int t = 0; t < 4; ++t) {
            acc[t] = __builtin_amdgcn_mfma_f32_16x16x32_bf16(a0, bfr[t][0], acc[t], 0, 0, 0);
            acc[t] = __builtin_amdgcn_mfma_f32_16x16x32_bf16(a1, bfr[t][1], acc[t], 0, 0, 0);
        }

        // activations: lane's valid slots are r=0,1 -> tile rows 4q+r, batch rows 2q+r
        unsigned short* hnx = hb[cur ^ 1];
        #pragma unroll
        for (int rr = 0; rr < 2; ++rr) {
            float ig = sigf(acc[0][rr]);
            float fg = sigf(acc[1][rr]);
            float gv = tanhf_(acc[2][rr]);
            float og = sigf(acc[3][rr]);
            float cv = fmaf(fg, cst[rr], ig * gv);
            cst[rr] = cv;
            float hv = og * tanhf_(cv);
            hnx[(4 * q + rr) * HS + n] = f2bf(hv);
            if (ts == TT - 1) hf[(2 * q + rr) * 65 + n] = hv;
        }
        cur ^= 1;
        __syncthreads();
    }

    // ---- head: out[b][o] = sum_n hf[b][n]*W_out[o][n] + b_out[o] ----
    if (tid < BT * 3) {
        int row = tid / 3, o = tid % 3;
        float s = b_out[o];
        #pragma unroll 8
        for (int k = 0; k < HH; ++k) s = fmaf(hf[row * 65 + k], W_out[o * 64 + k], s);
        out[(size_t)(bbase + row) * 3 + o] = s;
    }
}

extern "C" void kernel_launch(void* const* d_in, const int* in_sizes, int n_in,
                              void* d_out, int out_size, void* d_ws, size_t ws_size,
                              hipStream_t stream) {
    const float* x     = (const float*)d_in[0];
    const float* W_ih  = (const float*)d_in[1];
    const float* W_hh  = (const float*)d_in[2];
    const float* b_ih  = (const float*)d_in[3];
    const float* b_hh  = (const float*)d_in[4];
    const float* W_out = (const float*)d_in[5];
    const float* b_out = (const float*)d_in[6];
    float* out = (float*)d_out;
    hipLaunchKernelGGL(lstm_kernel, dim3(BATCH / BT), dim3(256), 0, stream,
                       x, W_ih, W_hh, b_ih, b_hh, W_out, b_out, out);
}

// Round 4
// 302.224 us; speedup vs baseline: 1.2752x; 1.0051x over previous
//
#include <hip/hip_runtime.h>

#define BATCH 4096
#define TT 512
#define HH 64
#define BT 4       // batch rows per block; batch j lives at MFMA tile row 4j so every
                   // lane's single valid C/D slot is r=0 (rows 4q+1..3 are zero rows)
#define XS 516     // x_s row stride in floats (16B-aligned rows)
#define HS 72      // h buffer row stride in bf16

typedef __attribute__((ext_vector_type(8))) short short8;
typedef __attribute__((ext_vector_type(4))) float floatx4;

__device__ __forceinline__ float sigf(float x) {
    return __builtin_amdgcn_rcpf(1.f + __builtin_amdgcn_exp2f(-1.44269504089f * x));
}
__device__ __forceinline__ float tanhf_(float x) {
    float e = __builtin_amdgcn_exp2f(2.88539008178f * x);   // e^(2x)
    return 1.f - 2.f * __builtin_amdgcn_rcpf(e + 1.f);
}
__device__ __forceinline__ unsigned short f2bf(float f) {   // RNE f32->bf16
    unsigned u = __float_as_uint(f);
    u = u + 0x7FFFu + ((u >> 16) & 1u);
    return (unsigned short)(u >> 16);
}

// 256 threads = 4 waves; grid 1024 = 4 independent blocks/CU (4 waves/SIMD with
// uncorrelated barriers). Wave w owns gate col-tiles {w,w+4,w+8,w+12}; each lane
// activates exactly one (batch q, hidden n=16w+c) cell.
__global__ __launch_bounds__(256, 4) void lstm_kernel(
    const float* __restrict__ x, const float* __restrict__ W_ih,
    const float* __restrict__ W_hh, const float* __restrict__ b_ih,
    const float* __restrict__ b_hh, const float* __restrict__ W_out,
    const float* __restrict__ b_out, float* __restrict__ out)
{
    __shared__ __align__(16) float x_s[BT * XS];             // 8.25 KB
    __shared__ __align__(16) unsigned short hb[2][16 * HS];  // 4.5 KB; rows m%4!=0 stay 0
    __shared__ __align__(16) float hf[BT * 65];              // final h fp32 for the head

    const int tid = threadIdx.x;
    const int w = tid >> 6;       // wave 0..3 -> gate col group
    const int l = tid & 63;
    const int q = l >> 4;         // this lane's batch row (0..3)
    const int c = l & 15;
    const int n = 16 * w + c;     // hidden index this lane activates
    const int bbase = blockIdx.x * BT;

    // ---- stage x[bbase..bbase+3][0..511] into LDS, coalesced float4 ----
    for (int i = 0; i < 2; ++i) {
        int flat = i * 256 + tid;              // 512 float4s
        int row = flat >> 7, c4 = flat & 127;
        const float4* xg = reinterpret_cast<const float4*>(x + (size_t)(bbase + row) * TT);
        float4 v = xg[c4];
        *reinterpret_cast<float4*>(&x_s[row * XS + c4 * 4]) = v;
    }
    for (int i = tid; i < 2 * 16 * HS; i += 256) hb[0][i] = 0;  // h0=0 + garbage rows of both bufs

    // ---- persistent B-fragments: W_hh rows for gates g = 64*t + n, bf16, in VGPRs ----
    short8 bfr[4][2];
    float wih[4], bb[4];
    for (int t = 0; t < 4; ++t) {
        int g = 64 * t + n;
        wih[t] = W_ih[g];
        bb[t] = b_ih[g] + b_hh[g];
        for (int ks = 0; ks < 2; ++ks) {
            const float* wp = W_hh + g * 64 + ks * 32 + q * 8;
            short8 v;
            #pragma unroll
            for (int j = 0; j < 8; ++j) v[j] = (short)f2bf(wp[j]);
            bfr[t][ks] = v;
        }
    }
    float cst = 0.f;              // c-state for (batch q, hidden n)

    // Persistent accumulators: slots 1..3 correspond to zero A-rows -> their MFMA
    // contribution is always 0; init once, never re-zero (saves 12 movs/step).
    floatx4 acc[4];
    #pragma unroll
    for (int t = 0; t < 4; ++t) acc[t] = floatx4{0.f, 0.f, 0.f, 0.f};

    __syncthreads();

    int cur = 0;
    for (int ts4 = 0; ts4 < TT; ts4 += 4) {
        // x for this lane's batch row, 4 timesteps at once (16B-aligned)
        float4 xq = *reinterpret_cast<const float4*>(&x_s[q * XS + ts4]);
        #pragma unroll
        for (int u = 0; u < 4; ++u) {
            const unsigned short* hc = hb[cur];
            short8 a0 = *reinterpret_cast<const short8*>(hc + c * HS + q * 8);
            short8 a1 = *reinterpret_cast<const short8*>(hc + c * HS + q * 8 + 32);

            float xv = (&xq.x)[u];
            #pragma unroll
            for (int t = 0; t < 4; ++t) acc[t][0] = fmaf(xv, wih[t], bb[t]);

            #pragma unroll
            for (int t = 0; t < 4; ++t) {
                acc[t] = __builtin_amdgcn_mfma_f32_16x16x32_bf16(a0, bfr[t][0], acc[t], 0, 0, 0);
                acc[t] = __builtin_amdgcn_mfma_f32_16x16x32_bf16(a1, bfr[t][1], acc[t], 0, 0, 0);
            }

            float ig = sigf(acc[0][0]);
            float fg = sigf(acc[1][0]);
            float gv = tanhf_(acc[2][0]);
            float og = sigf(acc[3][0]);
            float cv = fmaf(fg, cst, ig * gv);
            cst = cv;
            float hv = og * tanhf_(cv);
            hb[cur ^ 1][(4 * q) * HS + n] = f2bf(hv);
            if (ts4 + u == TT - 1) hf[q * 65 + n] = hv;   // uniform cond -> scalar branch
            cur ^= 1;
            __syncthreads();
        }
    }

    // ---- head: out[b][o] = sum_n hf[b][n]*W_out[o][n] + b_out[o] ----
    if (tid < BT * 3) {
        int row = tid / 3, o = tid % 3;
        float s = b_out[o];
        #pragma unroll 8
        for (int k = 0; k < HH; ++k) s = fmaf(hf[row * 65 + k], W_out[o * 64 + k], s);
        out[(size_t)(bbase + row) * 3 + o] = s;
    }
}

extern "C" void kernel_launch(void* const* d_in, const int* in_sizes, int n_in,
                              void* d_out, int out_size, void* d_ws, size_t ws_size,
                              hipStream_t stream) {
    const float* x     = (const float*)d_in[0];
    const float* W_ih  = (const float*)d_in[1];
    const float* W_hh  = (const float*)d_in[2];
    const float* b_ih  = (const float*)d_in[3];
    const float* b_hh  = (const float*)d_in[4];
    const float* W_out = (const float*)d_in[5];
    const float* b_out = (const float*)d_in[6];
    float* out = (float*)d_out;
    hipLaunchKernelGGL(lstm_kernel, dim3(BATCH / BT), dim3(256), 0, stream,
                       x, W_ih, W_hh, b_ih, b_hh, W_out, b_out, out);
}